// Round 14
// baseline (296.428 us; speedup 1.0000x reference)
//
#include <hip/hip_runtime.h>
#include <hip/hip_bf16.h>
#include <math.h>

#define NN 4096
#define MM 1024
#define BANDP 512

typedef float f4v __attribute__((ext_vector_type(4)));
typedef float f32x4 __attribute__((ext_vector_type(4)));
typedef short bf16x8 __attribute__((ext_vector_type(8)));
typedef short s4v __attribute__((ext_vector_type(4)));

__device__ __forceinline__ short f2b(float f) {
    union { float f; unsigned u; } v; v.f = f;
    unsigned r = v.u + 0x7fffu + ((v.u >> 16) & 1u);
    return (short)(r >> 16);
}
__device__ __forceinline__ float b2f(short s) {
    union { unsigned u; float f; } v;
    v.u = ((unsigned)(unsigned short)s) << 16;
    return v.f;
}
__device__ __forceinline__ float b2f_lo(unsigned p) {
    union { unsigned u; float f; } v; v.u = p << 16; return v.f;
}
__device__ __forceinline__ float b2f_hi(unsigned p) {
    union { unsigned u; float f; } v; v.u = p & 0xffff0000u; return v.f;
}

__device__ __forceinline__ void gl2lds16(const void* g, void* l) {
    __builtin_amdgcn_global_load_lds(
        (const __attribute__((address_space(1))) void*)g,
        (__attribute__((address_space(3))) void*)l, 16, 0, 0);
}

#define WAIT_VM8() asm volatile("s_waitcnt vmcnt(8)" ::: "memory")
#define WAIT_VM6() asm volatile("s_waitcnt vmcnt(6)" ::: "memory")
#define WAIT_VM4() asm volatile("s_waitcnt vmcnt(4)" ::: "memory")
#define WAIT_VM3() asm volatile("s_waitcnt vmcnt(3)" ::: "memory")
#define WAIT_VM0() asm volatile("s_waitcnt vmcnt(0)" ::: "memory")

// ---------------- fused prep: split x + trsplit Wq/Wofx/Wofy ----------------
// grid (32,32,7), block (32,8).
__global__ __launch_bounds__(256)
void prep_k(const float* __restrict__ x, const float* __restrict__ Wq,
            const float* __restrict__ Wofx, const float* __restrict__ Wofy,
            short* __restrict__ xh, short* __restrict__ xl,
            short* __restrict__ WqTh, short* __restrict__ WqTl,
            short* __restrict__ WofxyTh, short* __restrict__ WofxyTl)
{
    const int z = blockIdx.z;
    const int tx = threadIdx.x, ty = threadIdx.y;
    if (z >= 3) {
        const int b = (z - 3) * 1024 + blockIdx.y * 32 + blockIdx.x;
        const int tid = ty * 32 + tx;
        const int i = (b * 256 + tid) << 2;
        f4v v = *(const f4v*)&x[i];
        s4v hv, lv;
        #pragma unroll
        for (int q = 0; q < 4; ++q) {
            hv[q] = f2b(v[q]);
            lv[q] = f2b(v[q] - b2f(hv[q]));
        }
        *(s4v*)&xh[i] = hv;
        *(s4v*)&xl[i] = lv;
        return;
    }
    __shared__ float tile[32][33];
    const float* W = (z == 0) ? Wq : (z == 1) ? Wofx : Wofy;
    short* th = (z == 0) ? WqTh : WofxyTh + (size_t)(z - 1) * 1024 * 1024;
    short* tl = (z == 0) ? WqTl : WofxyTl + (size_t)(z - 1) * 1024 * 1024;
    const int bx = blockIdx.x << 5, by = blockIdx.y << 5;
    #pragma unroll
    for (int r = ty; r < 32; r += 8)
        tile[r][tx] = W[(size_t)(by + r) * MM + bx + tx];
    __syncthreads();
    #pragma unroll
    for (int r = ty; r < 32; r += 8) {
        const float v = tile[tx][r];
        const short h = f2b(v);
        th[(size_t)(bx + r) * MM + by + tx] = h;
        tl[(size_t)(bx + r) * MM + by + tx] = f2b(v - b2f(h));
    }
}

// ---------------- fused fp32->bf16 transpose of Wk|Wv|Wout ------------------
__global__ __launch_bounds__(256)
void transpose3_k(const float* __restrict__ Wk, const float* __restrict__ Wv,
                  const float* __restrict__ Wout, short* __restrict__ WkvT,
                  short* __restrict__ WoutT)
{
    __shared__ float tile[32][33];
    const int z = blockIdx.z;
    const float* W = (z == 0) ? Wk : (z == 1) ? Wv : Wout;
    short* dst = (z == 2) ? WoutT : WkvT + (size_t)z * 1024 * 1024;
    const int bx = blockIdx.x << 5, by = blockIdx.y << 5;
    const int tx = threadIdx.x, ty = threadIdx.y;
    #pragma unroll
    for (int r = ty; r < 32; r += 8)
        tile[r][tx] = W[(size_t)(by + r) * MM + bx + tx];
    __syncthreads();
    #pragma unroll
    for (int r = ty; r < 32; r += 8)
        dst[(size_t)(bx + r) * MM + by + tx] = f2b(tile[tx][r]);
}

// ---------------- split-bf16 3-term MFMA GEMM, BM=128 BN=128 ----------------
template<bool BIAS>
__global__ __launch_bounds__(256, 2)
void gemm_split(const short* __restrict__ Ah, const short* __restrict__ Al,
                const short* __restrict__ Bth, const short* __restrict__ Btl,
                const float* __restrict__ bias0, const float* __restrict__ bias1,
                short* __restrict__ outH, short* __restrict__ outL, int N)
{
    __shared__ short As[2][2][128 * 32];
    __shared__ short Bs[2][2][128 * 32];

    const int t  = threadIdx.x;
    const int l  = t & 63;
    const int w  = t >> 6;
    const int wm = w >> 1, wn = w & 1;
    const int lr = l & 15;
    const int lk = (l >> 4) << 3;
    const int lks = lk ^ (((l >> 1) & 3) << 3);   // swizzled read col (elems)

    const int i0 = blockIdx.y << 7;
    const int bn = blockIdx.x << 7;

    const int sr = t >> 2;
    const int sk = (((t & 3) ^ ((t >> 3) & 3)) << 3);  // inverse-swz source col

    const short* aH = Ah  + (size_t)(i0 + sr) * MM + sk;
    const short* aL = Al  + (size_t)(i0 + sr) * MM + sk;
    const short* bH = Bth + (size_t)(bn + sr) * MM + sk;
    const short* bL = Btl + (size_t)(bn + sr) * MM + sk;

    f32x4 acc[4][4] = {};

    auto stage = [&](int sb, int k0) {
        gl2lds16(aH + k0,           &As[sb][0][t * 8]);
        gl2lds16(aH + 64 * MM + k0, &As[sb][0][2048 + t * 8]);
        gl2lds16(aL + k0,           &As[sb][1][t * 8]);
        gl2lds16(aL + 64 * MM + k0, &As[sb][1][2048 + t * 8]);
        gl2lds16(bH + k0,           &Bs[sb][0][t * 8]);
        gl2lds16(bH + 64 * MM + k0, &Bs[sb][0][2048 + t * 8]);
        gl2lds16(bL + k0,           &Bs[sb][1][t * 8]);
        gl2lds16(bL + 64 * MM + k0, &Bs[sb][1][2048 + t * 8]);
    };
    stage(0, 0);

    for (int kt = 0; kt < 32; ++kt) {
        const int cur = kt & 1;
        if (kt + 1 < 32) { stage(cur ^ 1, (kt + 1) << 5); WAIT_VM8(); }
        else             { WAIT_VM0(); }
        __builtin_amdgcn_s_barrier();
        __builtin_amdgcn_sched_barrier(0);

        bf16x8 ah[4], al[4], bh[4], bl[4];
        #pragma unroll
        for (int i = 0; i < 4; ++i) {
            ah[i] = *(const bf16x8*)&As[cur][0][(wm * 64 + i * 16 + lr) * 32 + lks];
            al[i] = *(const bf16x8*)&As[cur][1][(wm * 64 + i * 16 + lr) * 32 + lks];
        }
        #pragma unroll
        for (int j = 0; j < 4; ++j) {
            bh[j] = *(const bf16x8*)&Bs[cur][0][(wn * 64 + j * 16 + lr) * 32 + lks];
            bl[j] = *(const bf16x8*)&Bs[cur][1][(wn * 64 + j * 16 + lr) * 32 + lks];
        }
        __builtin_amdgcn_s_setprio(1);
        #pragma unroll
        for (int i = 0; i < 4; ++i)
            #pragma unroll
            for (int j = 0; j < 4; ++j) {
                acc[i][j] = __builtin_amdgcn_mfma_f32_16x16x32_bf16(ah[i], bl[j], acc[i][j], 0, 0, 0);
                acc[i][j] = __builtin_amdgcn_mfma_f32_16x16x32_bf16(al[i], bh[j], acc[i][j], 0, 0, 0);
                acc[i][j] = __builtin_amdgcn_mfma_f32_16x16x32_bf16(ah[i], bh[j], acc[i][j], 0, 0, 0);
            }
        __builtin_amdgcn_s_setprio(0);
        __builtin_amdgcn_s_barrier();
    }

    const int rb = (l >> 4) << 2;
    #pragma unroll
    for (int i = 0; i < 4; ++i)
        #pragma unroll
        for (int j = 0; j < 4; ++j) {
            const int n = bn + wn * 64 + j * 16 + lr;
            float bv = 0.f;
            if (BIAS) bv = (n < 1024) ? bias0[n] : bias1[n - 1024];
            #pragma unroll
            for (int r = 0; r < 4; ++r) {
                const int m = i0 + wm * 64 + i * 16 + rb + r;
                const float v = acc[i][j][r] + bv;
                const short h = f2b(v);
                outH[(size_t)m * N + n] = h;
                outL[(size_t)m * N + n] = f2b(v - b2f(h));
            }
        }
}

// ---------------- split-bf16 3-term MFMA GEMM, BM=128 BN=64 (2 blk/CU) ------
__global__ __launch_bounds__(256, 2)
void gemm_split64(const short* __restrict__ Ah, const short* __restrict__ Al,
                  const short* __restrict__ Bth, const short* __restrict__ Btl,
                  short* __restrict__ outH, short* __restrict__ outL, int N)
{
    __shared__ short As[2][2][128 * 32];
    __shared__ short Bs[2][2][64 * 32];

    const int t  = threadIdx.x;
    const int l  = t & 63;
    const int w  = t >> 6;
    const int lr = l & 15;
    const int lk = (l >> 4) << 3;
    const int lks = lk ^ (((l >> 1) & 3) << 3);

    const int i0 = blockIdx.y << 7;
    const int bn = blockIdx.x << 6;

    const int sr = t >> 2;
    const int sk = (((t & 3) ^ ((t >> 3) & 3)) << 3);

    const short* aH = Ah  + (size_t)(i0 + sr) * MM + sk;
    const short* aL = Al  + (size_t)(i0 + sr) * MM + sk;
    const short* bH = Bth + (size_t)(bn + sr) * MM + sk;
    const short* bL = Btl + (size_t)(bn + sr) * MM + sk;

    f32x4 acc[2][4] = {};

    auto stage = [&](int sb, int k0) {
        gl2lds16(aH + k0,           &As[sb][0][t * 8]);
        gl2lds16(aH + 64 * MM + k0, &As[sb][0][2048 + t * 8]);
        gl2lds16(aL + k0,           &As[sb][1][t * 8]);
        gl2lds16(aL + 64 * MM + k0, &As[sb][1][2048 + t * 8]);
        gl2lds16(bH + k0,           &Bs[sb][0][t * 8]);
        gl2lds16(bL + k0,           &Bs[sb][1][t * 8]);
    };
    stage(0, 0);

    for (int kt = 0; kt < 32; ++kt) {
        const int cur = kt & 1;
        if (kt + 1 < 32) { stage(cur ^ 1, (kt + 1) << 5); WAIT_VM6(); }
        else             { WAIT_VM0(); }
        __builtin_amdgcn_s_barrier();
        __builtin_amdgcn_sched_barrier(0);

        bf16x8 ah[2], al[2], bh[4], bl[4];
        #pragma unroll
        for (int i = 0; i < 2; ++i) {
            ah[i] = *(const bf16x8*)&As[cur][0][(w * 32 + i * 16 + lr) * 32 + lks];
            al[i] = *(const bf16x8*)&As[cur][1][(w * 32 + i * 16 + lr) * 32 + lks];
        }
        #pragma unroll
        for (int j = 0; j < 4; ++j) {
            bh[j] = *(const bf16x8*)&Bs[cur][0][(j * 16 + lr) * 32 + lks];
            bl[j] = *(const bf16x8*)&Bs[cur][1][(j * 16 + lr) * 32 + lks];
        }
        __builtin_amdgcn_s_setprio(1);
        #pragma unroll
        for (int i = 0; i < 2; ++i)
            #pragma unroll
            for (int j = 0; j < 4; ++j) {
                acc[i][j] = __builtin_amdgcn_mfma_f32_16x16x32_bf16(ah[i], bl[j], acc[i][j], 0, 0, 0);
                acc[i][j] = __builtin_amdgcn_mfma_f32_16x16x32_bf16(al[i], bh[j], acc[i][j], 0, 0, 0);
                acc[i][j] = __builtin_amdgcn_mfma_f32_16x16x32_bf16(ah[i], bh[j], acc[i][j], 0, 0, 0);
            }
        __builtin_amdgcn_s_setprio(0);
        __builtin_amdgcn_s_barrier();
    }

    const int rb = (l >> 4) << 2;
    #pragma unroll
    for (int i = 0; i < 2; ++i)
        #pragma unroll
        for (int j = 0; j < 4; ++j) {
            const int n = bn + j * 16 + lr;
            #pragma unroll
            for (int r = 0; r < 4; ++r) {
                const int m = i0 + w * 32 + i * 16 + rb + r;
                const float v = acc[i][j][r];
                const short h = f2b(v);
                outH[(size_t)m * N + n] = h;
                outL[(size_t)m * N + n] = f2b(v - b2f(h));
            }
        }
}

// ---------------- plain bf16 GEMM, BM=128 BN=64, fp32 out (final GEMM) ------
__global__ __launch_bounds__(256, 2)
void gemm64_f32out(const short* __restrict__ A, const short* __restrict__ Bt,
                   float* __restrict__ C)
{
    __shared__ short As[2][128 * 32];
    __shared__ short Bs[2][64 * 32];

    const int t  = threadIdx.x;
    const int l  = t & 63;
    const int w  = t >> 6;
    const int lr = l & 15;
    const int lk = (l >> 4) << 3;
    const int lks = lk ^ (((l >> 1) & 3) << 3);

    const int i0 = blockIdx.y << 7;
    const int bn = blockIdx.x << 6;

    const int sr = t >> 2;
    const int sk = (((t & 3) ^ ((t >> 3) & 3)) << 3);

    const short* aS = A  + (size_t)(i0 + sr) * MM + sk;
    const short* bS = Bt + (size_t)(bn + sr) * MM + sk;

    f32x4 acc[2][4] = {};

    auto stage = [&](int sb, int k0) {
        gl2lds16(aS + k0,           &As[sb][0] + t * 8);
        gl2lds16(aS + 64 * MM + k0, &As[sb][0] + 2048 + t * 8);
        gl2lds16(bS + k0,           &Bs[sb][0] + t * 8);
    };
    stage(0, 0);

    for (int kt = 0; kt < 32; ++kt) {
        const int cur = kt & 1;
        if (kt + 1 < 32) { stage(cur ^ 1, (kt + 1) << 5); WAIT_VM3(); }
        else             { WAIT_VM0(); }
        __builtin_amdgcn_s_barrier();
        __builtin_amdgcn_sched_barrier(0);

        bf16x8 a[2], b[4];
        #pragma unroll
        for (int i = 0; i < 2; ++i)
            a[i] = *(const bf16x8*)&As[cur][(w * 32 + i * 16 + lr) * 32 + lks];
        #pragma unroll
        for (int j = 0; j < 4; ++j)
            b[j] = *(const bf16x8*)&Bs[cur][(j * 16 + lr) * 32 + lks];
        __builtin_amdgcn_s_setprio(1);
        #pragma unroll
        for (int i = 0; i < 2; ++i)
            #pragma unroll
            for (int j = 0; j < 4; ++j)
                acc[i][j] = __builtin_amdgcn_mfma_f32_16x16x32_bf16(a[i], b[j], acc[i][j], 0, 0, 0);
        __builtin_amdgcn_s_setprio(0);
        __builtin_amdgcn_s_barrier();
    }

    const int rb = (l >> 4) << 2;
    #pragma unroll
    for (int i = 0; i < 2; ++i)
        #pragma unroll
        for (int j = 0; j < 4; ++j) {
            const int n = bn + j * 16 + lr;
            #pragma unroll
            for (int r = 0; r < 4; ++r) {
                const int m = i0 + w * 32 + i * 16 + rb + r;
                C[(size_t)m * MM + n] = acc[i][j][r];
            }
        }
}

// ---------------- bilinear grid sample, 8 samples/thread, 16-deep MLP -------
// grid 2048 blocks; block row i = bid*2 + (tid>>7), cols jb = (tid&127)*8.
// Phase 1: compute all 16 addresses; Phase 2: issue all 16 scattered dword
// loads back-to-back; Phase 3: interpolate. Values bit-identical to R13.
__global__ __launch_bounds__(256)
void grid_sample_k(const short* __restrict__ xh, const short* __restrict__ ofh,
                   const short* __restrict__ ofl, short* __restrict__ xnb)
{
    const int tid = threadIdx.x;
    const int i = (blockIdx.x << 1) | (tid >> 7);
    const int jb = (tid & 127) << 3;

    const short* rh = ofh + (size_t)i * 2048;
    const short* rl = ofl + (size_t)i * 2048;
    bf16x8 hx = *(const bf16x8*)&rh[jb];
    bf16x8 lx = *(const bf16x8*)&rl[jb];
    bf16x8 hy = *(const bf16x8*)&rh[1024 + jb];
    bf16x8 ly = *(const bf16x8*)&rl[1024 + jb];

    const float gxb = (2.0f * (float)i) / (float)NN - 1.0f;

    const short* r0p[8];
    const short* r1p[8];
    float wxv[8], wyv[8];
    bool edge[8];

    #pragma unroll
    for (int q = 0; q < 8; ++q) {
        const int j = jb + q;
        float gx = gxb + b2f(hx[q]) + b2f(lx[q]);
        gx = fminf(fmaxf(gx, -1.0f), 1.0f);
        float gy = (2.0f * (float)j) / (float)MM - 1.0f + b2f(hy[q]) + b2f(ly[q]);
        gy = fminf(fmaxf(gy, -1.0f), 1.0f);

        const float ixf = (gx + 1.0f) * 511.5f;
        const float iyf = (gy + 1.0f) * 2047.5f;
        const float ix0 = floorf(ixf);
        const float iy0 = floorf(iyf);
        wxv[q] = ixf - ix0;
        wyv[q] = iyf - iy0;
        int ix0i = (int)ix0; ix0i = max(0, min(ix0i, MM - 1));
        int iy0i = (int)iy0; iy0i = max(0, min(iy0i, NN - 1));
        const int iy1i = min(iy0i + 1, NN - 1);
        const int wb = min(ix0i, MM - 2);
        edge[q] = ix0i > wb;
        r0p[q] = xh + (size_t)iy0i * MM + wb;
        r1p[q] = xh + (size_t)iy1i * MM + wb;
    }

    unsigned w0[8], w1[8];
    #pragma unroll
    for (int q = 0; q < 8; ++q) {
        __builtin_memcpy(&w0[q], r0p[q], 4);
        __builtin_memcpy(&w1[q], r1p[q], 4);
    }

    bf16x8 out;
    #pragma unroll
    for (int q = 0; q < 8; ++q) {
        const float v01 = b2f_hi(w0[q]);
        const float v11 = b2f_hi(w1[q]);
        const float v00 = edge[q] ? v01 : b2f_lo(w0[q]);
        const float v10 = edge[q] ? v11 : b2f_lo(w1[q]);
        out[q] = f2b((1.0f - wyv[q]) * ((1.0f - wxv[q]) * v00 + wxv[q] * v01)
                   + wyv[q] * ((1.0f - wxv[q]) * v10 + wxv[q] * v11));
    }
    *(bf16x8*)&xnb[(size_t)i * MM + jb] = out;
}

// ---------------- bf16 MFMA GEMM, BM=128 BN=128 -----------------------------
// MODE 3: banded logits -> C0 band fp32 [4096][512] with -inf mask; Bt=K
// MODE 4: fused K|V: n<1024 -> C0 = K bf16 [4096][1024]; else C1 = Vt bf16 [1024][4096]
template<int MODE>
__global__ __launch_bounds__(256, 2)
void mfma_gemm(const short* __restrict__ A, const short* __restrict__ Bt,
               void* __restrict__ C0, void* __restrict__ C1)
{
    __shared__ short As[2][128 * 32];
    __shared__ short Bs[2][128 * 32];

    const int t  = threadIdx.x;
    const int l  = t & 63;
    const int w  = t >> 6;
    const int wm = w >> 1, wn = w & 1;
    const int lr = l & 15;
    const int lk = (l >> 4) << 3;
    const int lks = lk ^ (((l >> 1) & 3) << 3);

    const int i0 = blockIdx.y << 7;
    const int bn = blockIdx.x << 7;
    const int jb = (MODE == 3) ? (i0 - 256 + bn) : bn;

    const int sr = t >> 2;
    const int sk = (((t & 3) ^ ((t >> 3) & 3)) << 3);

    const short* aS = A + (size_t)(i0 + sr) * MM + sk;
    int br0 = jb + sr, br1 = jb + sr + 64;
    if (MODE == 3) {
        br0 = min(max(br0, 0), NN - 1);
        br1 = min(max(br1, 0), NN - 1);
    }
    const short* bS0 = Bt + (size_t)br0 * MM + sk;
    const short* bS1 = Bt + (size_t)br1 * MM + sk;

    f32x4 acc[4][4] = {};

    auto stage = [&](int sb, int k0) {
        gl2lds16(aS + k0,           &As[sb][0] + t * 8);
        gl2lds16(aS + 64 * MM + k0, &As[sb][0] + 2048 + t * 8);
        gl2lds16(bS0 + k0,          &Bs[sb][0] + t * 8);
        gl2lds16(bS1 + k0,          &Bs[sb][0] + 2048 + t * 8);
    };
    stage(0, 0);

    for (int kt = 0; kt < 32; ++kt) {
        const int cur = kt & 1;
        if (kt + 1 < 32) { stage(cur ^ 1, (kt + 1) << 5); WAIT_VM4(); }
        else             { WAIT_VM0(); }
        __builtin_amdgcn_s_barrier();
        __builtin_amdgcn_sched_barrier(0);

        bf16x8 a[4], b[4];
        #pragma unroll
        for (int i = 0; i < 4; ++i)
            a[i] = *(const bf16x8*)&As[cur][(wm * 64 + i * 16 + lr) * 32 + lks];
        #pragma unroll
        for (int j = 0; j < 4; ++j)
            b[j] = *(const bf16x8*)&Bs[cur][(wn * 64 + j * 16 + lr) * 32 + lks];
        __builtin_amdgcn_s_setprio(1);
        #pragma unroll
        for (int i = 0; i < 4; ++i)
            #pragma unroll
            for (int j = 0; j < 4; ++j)
                acc[i][j] = __builtin_amdgcn_mfma_f32_16x16x32_bf16(a[i], b[j], acc[i][j], 0, 0, 0);
        __builtin_amdgcn_s_setprio(0);
        __builtin_amdgcn_s_barrier();
    }

    const int rb = (l >> 4) << 2;
    #pragma unroll
    for (int i = 0; i < 4; ++i) {
        #pragma unroll
        for (int j = 0; j < 4; ++j) {
            const int nl = wn * 64 + j * 16 + lr;
            if (MODE == 4 && bn + nl >= 1024) {
                const int m0 = i0 + wm * 64 + i * 16 + rb;
                s4v o;
                #pragma unroll
                for (int r = 0; r < 4; ++r) o[r] = f2b(acc[i][j][r]);
                *(s4v*)&((short*)C1)[(size_t)(bn + nl - 1024) * NN + m0] = o;
            } else {
                #pragma unroll
                for (int r = 0; r < 4; ++r) {
                    const int m = i0 + wm * 64 + i * 16 + rb + r;
                    const float v = acc[i][j][r];
                    if (MODE == 4) {
                        ((short*)C0)[(size_t)m * MM + bn + nl] = f2b(v);
                    } else if (MODE == 3) {
                        const int jj = jb + nl;
                        const int ci = jj - m + 255;
                        if (ci >= 0 && ci <= 510)
                            ((float*)C0)[(size_t)m * BANDP + ci] =
                                (jj >= 0 && jj < NN) ? 0.06f * v : -INFINITY;
                    }
                }
            }
        }
    }
}

// ---------------- softmax over band; scatter att values + bandT -------------
__global__ __launch_bounds__(256)
void band_softmax(const float* __restrict__ band, float* __restrict__ att,
                  short* __restrict__ bandT)
{
    const int i = blockIdx.x;
    const int tid = threadIdx.x;
    const float* brow = band + (size_t)i * BANDP;

    float v0 = brow[tid];
    float v1 = (tid < 255) ? brow[tid + 256] : -INFINITY;

    float m = fmaxf(v0, v1);
    #pragma unroll
    for (int o = 32; o >= 1; o >>= 1) m = fmaxf(m, __shfl_xor(m, o));
    __shared__ float redm[4], reds[4];
    const int wv = tid >> 6, ln = tid & 63;
    if (ln == 0) redm[wv] = m;
    __syncthreads();
    m = fmaxf(fmaxf(redm[0], redm[1]), fmaxf(redm[2], redm[3]));

    float p0 = expf(v0 - m);
    float p1 = (tid < 255) ? expf(v1 - m) : 0.f;
    float s = p0 + p1;
    #pragma unroll
    for (int o = 32; o >= 1; o >>= 1) s += __shfl_xor(s, o);
    if (ln == 0) reds[wv] = s;
    __syncthreads();
    s = reds[0] + reds[1] + reds[2] + reds[3];
    const float rinv = 1.0f / s;
    p0 *= rinv; p1 *= rinv;

    float* arow = att + (size_t)i * NN;
    int j = i + tid - 255;
    if (j >= 0 && j < NN) {
        arow[j] = p0;
        bandT[(size_t)j * 768 + (i - (j & ~7) + 384)] = f2b(p0);
    }
    j = i + tid + 1;
    if (tid < 255 && j >= 0 && j < NN) {
        arow[j] = p1;
        bandT[(size_t)j * 768 + (i - (j & ~7) + 384)] = f2b(p1);
    }
}

// ---------------- y1 = att^T @ V via MFMA, direct-global operands -----------
__global__ __launch_bounds__(256, 2)
void attT_v_mfma(const short* __restrict__ bandT, const short* __restrict__ Vt,
                 short* __restrict__ y1b)
{
    const int t = threadIdx.x, l = t & 63, w = t >> 6;
    const int wm = w >> 1, wn = w & 1;
    const int lr = l & 15, lk = (l >> 4) << 3;
    const int r0 = blockIdx.y << 7;
    const int n0 = blockIdx.x << 6;

    f32x4 acc[4][2] = {};
    for (int ks = 0; ks < 20; ++ks) {
        const int j0 = r0 - 256 + (ks << 5);
        if (j0 < 0 || j0 >= NN) continue;
        bf16x8 b[2];
        #pragma unroll
        for (int j = 0; j < 2; ++j)
            b[j] = *(const bf16x8*)&Vt[(size_t)(n0 + wn * 32 + j * 16 + lr) * NN + j0 + lk];
        #pragma unroll
        for (int i = 0; i < 4; ++i) {
            const int r = r0 + wm * 64 + i * 16 + lr;
            const int cc = j0 + lk - (r & ~7) + 384;
            bf16x8 a = *(const bf16x8*)&bandT[(size_t)r * 768 + cc];
            #pragma unroll
            for (int j = 0; j < 2; ++j)
                acc[i][j] = __builtin_amdgcn_mfma_f32_16x16x32_bf16(a, b[j], acc[i][j], 0, 0, 0);
        }
    }
    const int rb = (l >> 4) << 2;
    #pragma unroll
    for (int i = 0; i < 4; ++i)
        #pragma unroll
        for (int j = 0; j < 2; ++j)
            #pragma unroll
            for (int r = 0; r < 4; ++r)
                y1b[(size_t)(r0 + wm * 64 + i * 16 + rb + r) * MM + n0 + wn * 32 + j * 16 + lr]
                    = f2b(acc[i][j][r]);
}

extern "C" void kernel_launch(void* const* d_in, const int* in_sizes, int n_in,
                              void* d_out, int out_size, void* d_ws, size_t ws_size,
                              hipStream_t stream)
{
    const float* x    = (const float*)d_in[0];
    const float* Wq   = (const float*)d_in[1];
    const float* Wk   = (const float*)d_in[2];
    const float* Wv   = (const float*)d_in[3];
    const float* Wofx = (const float*)d_in[4];
    const float* bofx = (const float*)d_in[5];
    const float* Wofy = (const float*)d_in[6];
    const float* bofy = (const float*)d_in[7];
    const float* Wout = (const float*)d_in[8];

    float* y_out   = (float*)d_out;
    float* att_out = (float*)d_out + (size_t)NN * MM;

    char* wsb = (char*)d_ws;
    const size_t MB = 1024 * 1024;
    // Layout identical to R13 (liveness-verified, peak 64 MB at ofxy-GEMM):
    short* xh      = (short*)(wsb + 0);         // 8 MB
    short* Qh      = (short*)(wsb + 8 * MB);    // 8 MB
    short* Ql      = (short*)(wsb + 16 * MB);   // 8 MB
    short* WofxyTh = (short*)(wsb + 24 * MB);   // 4 MB (2 planes)
    short* WofxyTl = (short*)(wsb + 28 * MB);   // 4 MB
    short* xl      = (short*)(wsb + 32 * MB);   // 8 MB (dead after Q-GEMM)
    short* WqTh    = (short*)(wsb + 40 * MB);   // 2 MB
    short* WqTl    = (short*)(wsb + 42 * MB);   // 2 MB
    short* ofxyh   = (short*)(wsb + 32 * MB);   // 16 MB (over xl/WqT dead)
    short* ofxyl   = (short*)(wsb + 48 * MB);   // 16 MB
    short* xnb     = (short*)(wsb + 16 * MB);   // 8 MB (over Ql dead)
    short* WkvT    = (short*)(wsb + 24 * MB);   // 4 MB (over WofxyT dead)
    short* WoutT   = (short*)(wsb + 28 * MB);   // 2 MB
    short* Kb      = (short*)(wsb + 32 * MB);   // 8 MB (over ofxyh dead)
    short* Vtb     = (short*)(wsb + 40 * MB);   // 8 MB
    float* band    = (float*)(wsb + 48 * MB);   // 8 MB (over ofxyl dead)
    short* bandT   = (short*)(wsb + 56 * MB);   // 6 MB
    short* y1b     = (short*)(wsb + 16 * MB);   // 8 MB (over xnb dead)

    const dim3 blk(256);
    const dim3 tblk(32, 8);

    // ---- fused prep: split x + trsplit Wq/Wofx/Wofy ----
    prep_k<<<dim3(32, 32, 7), tblk, 0, stream>>>(
        x, Wq, Wofx, Wofy, xh, xl, WqTh, WqTl, WofxyTh, WofxyTl);

    // ---- sensitive path via split-bf16 MFMA ----
    gemm_split64<<<dim3(16, 32), blk, 0, stream>>>(
        xh, xl, WqTh, WqTl, Qh, Ql, 1024);
    gemm_split<true><<<dim3(16, 32), blk, 0, stream>>>(
        Qh, Ql, WofxyTh, WofxyTl, bofx, bofy, ofxyh, ofxyl, 2048);

    // gather, 8 samples/thread with 16-deep load pipelining
    grid_sample_k<<<dim3(NN / 2), blk, 0, stream>>>(xh, ofxyh, ofxyl, xnb);

    // ---- bf16 path ----
    transpose3_k<<<dim3(32, 32, 3), tblk, 0, stream>>>(Wk, Wv, Wout, WkvT, WoutT);

    // K | Vt fused
    mfma_gemm<4><<<dim3(16, 32), blk, 0, stream>>>(xnb, WkvT, Kb, Vtb);
    // banded logits
    mfma_gemm<3><<<dim3(5, 32), blk, 0, stream>>>(Qh, Kb, band, nullptr);
    // zero att region (64 MB) + bandT, then scatter-only softmax
    hipMemsetAsync(att_out, 0, (size_t)NN * NN * sizeof(float), stream);
    hipMemsetAsync(bandT, 0, (size_t)NN * 768 * sizeof(short), stream);
    band_softmax<<<dim3(NN), blk, 0, stream>>>(band, att_out, bandT);
    // y1 = att^T @ V
    attT_v_mfma<<<dim3(16, 32), blk, 0, stream>>>(bandT, Vtb, y1b);
    // y = y1 @ Wout
    gemm64_f32out<<<dim3(16, 32), blk, 0, stream>>>(y1b, WoutT, y_out);
}

// Round 15
// 294.458 us; speedup vs baseline: 1.0067x; 1.0067x over previous
//
#include <hip/hip_runtime.h>
#include <hip/hip_bf16.h>
#include <math.h>

#define NN 4096
#define MM 1024
#define BANDP 512

typedef float f4v __attribute__((ext_vector_type(4)));
typedef float f32x4 __attribute__((ext_vector_type(4)));
typedef short bf16x8 __attribute__((ext_vector_type(8)));
typedef short s4v __attribute__((ext_vector_type(4)));

__device__ __forceinline__ short f2b(float f) {
    union { float f; unsigned u; } v; v.f = f;
    unsigned r = v.u + 0x7fffu + ((v.u >> 16) & 1u);
    return (short)(r >> 16);
}
__device__ __forceinline__ float b2f(short s) {
    union { unsigned u; float f; } v;
    v.u = ((unsigned)(unsigned short)s) << 16;
    return v.f;
}
__device__ __forceinline__ float b2f_lo(unsigned p) {
    union { unsigned u; float f; } v; v.u = p << 16; return v.f;
}
__device__ __forceinline__ float b2f_hi(unsigned p) {
    union { unsigned u; float f; } v; v.u = p & 0xffff0000u; return v.f;
}

__device__ __forceinline__ void gl2lds16(const void* g, void* l) {
    __builtin_amdgcn_global_load_lds(
        (const __attribute__((address_space(1))) void*)g,
        (__attribute__((address_space(3))) void*)l, 16, 0, 0);
}

#define WAIT_VM8() asm volatile("s_waitcnt vmcnt(8)" ::: "memory")
#define WAIT_VM6() asm volatile("s_waitcnt vmcnt(6)" ::: "memory")
#define WAIT_VM4() asm volatile("s_waitcnt vmcnt(4)" ::: "memory")
#define WAIT_VM3() asm volatile("s_waitcnt vmcnt(3)" ::: "memory")
#define WAIT_VM0() asm volatile("s_waitcnt vmcnt(0)" ::: "memory")

// ---------------- fused prep: split x + trsplit Wq/Wofx/Wofy ----------------
// grid (32,32,7), block (32,8).
__global__ __launch_bounds__(256)
void prep_k(const float* __restrict__ x, const float* __restrict__ Wq,
            const float* __restrict__ Wofx, const float* __restrict__ Wofy,
            short* __restrict__ xh, short* __restrict__ xl,
            short* __restrict__ WqTh, short* __restrict__ WqTl,
            short* __restrict__ WofxyTh, short* __restrict__ WofxyTl)
{
    const int z = blockIdx.z;
    const int tx = threadIdx.x, ty = threadIdx.y;
    if (z >= 3) {
        const int b = (z - 3) * 1024 + blockIdx.y * 32 + blockIdx.x;
        const int tid = ty * 32 + tx;
        const int i = (b * 256 + tid) << 2;
        f4v v = *(const f4v*)&x[i];
        s4v hv, lv;
        #pragma unroll
        for (int q = 0; q < 4; ++q) {
            hv[q] = f2b(v[q]);
            lv[q] = f2b(v[q] - b2f(hv[q]));
        }
        *(s4v*)&xh[i] = hv;
        *(s4v*)&xl[i] = lv;
        return;
    }
    __shared__ float tile[32][33];
    const float* W = (z == 0) ? Wq : (z == 1) ? Wofx : Wofy;
    short* th = (z == 0) ? WqTh : WofxyTh + (size_t)(z - 1) * 1024 * 1024;
    short* tl = (z == 0) ? WqTl : WofxyTl + (size_t)(z - 1) * 1024 * 1024;
    const int bx = blockIdx.x << 5, by = blockIdx.y << 5;
    #pragma unroll
    for (int r = ty; r < 32; r += 8)
        tile[r][tx] = W[(size_t)(by + r) * MM + bx + tx];
    __syncthreads();
    #pragma unroll
    for (int r = ty; r < 32; r += 8) {
        const float v = tile[tx][r];
        const short h = f2b(v);
        th[(size_t)(bx + r) * MM + by + tx] = h;
        tl[(size_t)(bx + r) * MM + by + tx] = f2b(v - b2f(h));
    }
}

// ---------------- fused fp32->bf16 transpose of Wk|Wv|Wout ------------------
__global__ __launch_bounds__(256)
void transpose3_k(const float* __restrict__ Wk, const float* __restrict__ Wv,
                  const float* __restrict__ Wout, short* __restrict__ WkvT,
                  short* __restrict__ WoutT)
{
    __shared__ float tile[32][33];
    const int z = blockIdx.z;
    const float* W = (z == 0) ? Wk : (z == 1) ? Wv : Wout;
    short* dst = (z == 2) ? WoutT : WkvT + (size_t)z * 1024 * 1024;
    const int bx = blockIdx.x << 5, by = blockIdx.y << 5;
    const int tx = threadIdx.x, ty = threadIdx.y;
    #pragma unroll
    for (int r = ty; r < 32; r += 8)
        tile[r][tx] = W[(size_t)(by + r) * MM + bx + tx];
    __syncthreads();
    #pragma unroll
    for (int r = ty; r < 32; r += 8)
        dst[(size_t)(bx + r) * MM + by + tx] = f2b(tile[tx][r]);
}

// ---------------- split-bf16 3-term MFMA GEMM, BM=128 BN=128 ----------------
template<bool BIAS>
__global__ __launch_bounds__(256, 2)
void gemm_split(const short* __restrict__ Ah, const short* __restrict__ Al,
                const short* __restrict__ Bth, const short* __restrict__ Btl,
                const float* __restrict__ bias0, const float* __restrict__ bias1,
                short* __restrict__ outH, short* __restrict__ outL, int N)
{
    __shared__ short As[2][2][128 * 32];
    __shared__ short Bs[2][2][128 * 32];

    const int t  = threadIdx.x;
    const int l  = t & 63;
    const int w  = t >> 6;
    const int wm = w >> 1, wn = w & 1;
    const int lr = l & 15;
    const int lk = (l >> 4) << 3;
    const int lks = lk ^ (((l >> 1) & 3) << 3);   // swizzled read col (elems)

    const int i0 = blockIdx.y << 7;
    const int bn = blockIdx.x << 7;

    const int sr = t >> 2;
    const int sk = (((t & 3) ^ ((t >> 3) & 3)) << 3);  // inverse-swz source col

    const short* aH = Ah  + (size_t)(i0 + sr) * MM + sk;
    const short* aL = Al  + (size_t)(i0 + sr) * MM + sk;
    const short* bH = Bth + (size_t)(bn + sr) * MM + sk;
    const short* bL = Btl + (size_t)(bn + sr) * MM + sk;

    f32x4 acc[4][4] = {};

    auto stage = [&](int sb, int k0) {
        gl2lds16(aH + k0,           &As[sb][0][t * 8]);
        gl2lds16(aH + 64 * MM + k0, &As[sb][0][2048 + t * 8]);
        gl2lds16(aL + k0,           &As[sb][1][t * 8]);
        gl2lds16(aL + 64 * MM + k0, &As[sb][1][2048 + t * 8]);
        gl2lds16(bH + k0,           &Bs[sb][0][t * 8]);
        gl2lds16(bH + 64 * MM + k0, &Bs[sb][0][2048 + t * 8]);
        gl2lds16(bL + k0,           &Bs[sb][1][t * 8]);
        gl2lds16(bL + 64 * MM + k0, &Bs[sb][1][2048 + t * 8]);
    };
    stage(0, 0);

    for (int kt = 0; kt < 32; ++kt) {
        const int cur = kt & 1;
        if (kt + 1 < 32) { stage(cur ^ 1, (kt + 1) << 5); WAIT_VM8(); }
        else             { WAIT_VM0(); }
        __builtin_amdgcn_s_barrier();
        __builtin_amdgcn_sched_barrier(0);

        bf16x8 ah[4], al[4], bh[4], bl[4];
        #pragma unroll
        for (int i = 0; i < 4; ++i) {
            ah[i] = *(const bf16x8*)&As[cur][0][(wm * 64 + i * 16 + lr) * 32 + lks];
            al[i] = *(const bf16x8*)&As[cur][1][(wm * 64 + i * 16 + lr) * 32 + lks];
        }
        #pragma unroll
        for (int j = 0; j < 4; ++j) {
            bh[j] = *(const bf16x8*)&Bs[cur][0][(wn * 64 + j * 16 + lr) * 32 + lks];
            bl[j] = *(const bf16x8*)&Bs[cur][1][(wn * 64 + j * 16 + lr) * 32 + lks];
        }
        __builtin_amdgcn_s_setprio(1);
        #pragma unroll
        for (int i = 0; i < 4; ++i)
            #pragma unroll
            for (int j = 0; j < 4; ++j) {
                acc[i][j] = __builtin_amdgcn_mfma_f32_16x16x32_bf16(ah[i], bl[j], acc[i][j], 0, 0, 0);
                acc[i][j] = __builtin_amdgcn_mfma_f32_16x16x32_bf16(al[i], bh[j], acc[i][j], 0, 0, 0);
                acc[i][j] = __builtin_amdgcn_mfma_f32_16x16x32_bf16(ah[i], bh[j], acc[i][j], 0, 0, 0);
            }
        __builtin_amdgcn_s_setprio(0);
        __builtin_amdgcn_s_barrier();
    }

    const int rb = (l >> 4) << 2;
    #pragma unroll
    for (int i = 0; i < 4; ++i)
        #pragma unroll
        for (int j = 0; j < 4; ++j) {
            const int n = bn + wn * 64 + j * 16 + lr;
            float bv = 0.f;
            if (BIAS) bv = (n < 1024) ? bias0[n] : bias1[n - 1024];
            #pragma unroll
            for (int r = 0; r < 4; ++r) {
                const int m = i0 + wm * 64 + i * 16 + rb + r;
                const float v = acc[i][j][r] + bv;
                const short h = f2b(v);
                outH[(size_t)m * N + n] = h;
                outL[(size_t)m * N + n] = f2b(v - b2f(h));
            }
        }
}

// ---------------- split-bf16 3-term MFMA GEMM, BM=128 BN=64 (2 blk/CU) ------
__global__ __launch_bounds__(256, 2)
void gemm_split64(const short* __restrict__ Ah, const short* __restrict__ Al,
                  const short* __restrict__ Bth, const short* __restrict__ Btl,
                  short* __restrict__ outH, short* __restrict__ outL, int N)
{
    __shared__ short As[2][2][128 * 32];
    __shared__ short Bs[2][2][64 * 32];

    const int t  = threadIdx.x;
    const int l  = t & 63;
    const int w  = t >> 6;
    const int lr = l & 15;
    const int lk = (l >> 4) << 3;
    const int lks = lk ^ (((l >> 1) & 3) << 3);

    const int i0 = blockIdx.y << 7;
    const int bn = blockIdx.x << 6;

    const int sr = t >> 2;
    const int sk = (((t & 3) ^ ((t >> 3) & 3)) << 3);

    const short* aH = Ah  + (size_t)(i0 + sr) * MM + sk;
    const short* aL = Al  + (size_t)(i0 + sr) * MM + sk;
    const short* bH = Bth + (size_t)(bn + sr) * MM + sk;
    const short* bL = Btl + (size_t)(bn + sr) * MM + sk;

    f32x4 acc[2][4] = {};

    auto stage = [&](int sb, int k0) {
        gl2lds16(aH + k0,           &As[sb][0][t * 8]);
        gl2lds16(aH + 64 * MM + k0, &As[sb][0][2048 + t * 8]);
        gl2lds16(aL + k0,           &As[sb][1][t * 8]);
        gl2lds16(aL + 64 * MM + k0, &As[sb][1][2048 + t * 8]);
        gl2lds16(bH + k0,           &Bs[sb][0][t * 8]);
        gl2lds16(bL + k0,           &Bs[sb][1][t * 8]);
    };
    stage(0, 0);

    for (int kt = 0; kt < 32; ++kt) {
        const int cur = kt & 1;
        if (kt + 1 < 32) { stage(cur ^ 1, (kt + 1) << 5); WAIT_VM6(); }
        else             { WAIT_VM0(); }
        __builtin_amdgcn_s_barrier();
        __builtin_amdgcn_sched_barrier(0);

        bf16x8 ah[2], al[2], bh[4], bl[4];
        #pragma unroll
        for (int i = 0; i < 2; ++i) {
            ah[i] = *(const bf16x8*)&As[cur][0][(w * 32 + i * 16 + lr) * 32 + lks];
            al[i] = *(const bf16x8*)&As[cur][1][(w * 32 + i * 16 + lr) * 32 + lks];
        }
        #pragma unroll
        for (int j = 0; j < 4; ++j) {
            bh[j] = *(const bf16x8*)&Bs[cur][0][(j * 16 + lr) * 32 + lks];
            bl[j] = *(const bf16x8*)&Bs[cur][1][(j * 16 + lr) * 32 + lks];
        }
        __builtin_amdgcn_s_setprio(1);
        #pragma unroll
        for (int i = 0; i < 2; ++i)
            #pragma unroll
            for (int j = 0; j < 4; ++j) {
                acc[i][j] = __builtin_amdgcn_mfma_f32_16x16x32_bf16(ah[i], bl[j], acc[i][j], 0, 0, 0);
                acc[i][j] = __builtin_amdgcn_mfma_f32_16x16x32_bf16(al[i], bh[j], acc[i][j], 0, 0, 0);
                acc[i][j] = __builtin_amdgcn_mfma_f32_16x16x32_bf16(ah[i], bh[j], acc[i][j], 0, 0, 0);
            }
        __builtin_amdgcn_s_setprio(0);
        __builtin_amdgcn_s_barrier();
    }

    const int rb = (l >> 4) << 2;
    #pragma unroll
    for (int i = 0; i < 2; ++i)
        #pragma unroll
        for (int j = 0; j < 4; ++j) {
            const int n = bn + j * 16 + lr;
            #pragma unroll
            for (int r = 0; r < 4; ++r) {
                const int m = i0 + w * 32 + i * 16 + rb + r;
                const float v = acc[i][j][r];
                const short h = f2b(v);
                outH[(size_t)m * N + n] = h;
                outL[(size_t)m * N + n] = f2b(v - b2f(h));
            }
        }
}

// ---------------- plain bf16 GEMM, BM=128 BN=64, fp32 out (final GEMM) ------
__global__ __launch_bounds__(256, 2)
void gemm64_f32out(const short* __restrict__ A, const short* __restrict__ Bt,
                   float* __restrict__ C)
{
    __shared__ short As[2][128 * 32];
    __shared__ short Bs[2][64 * 32];

    const int t  = threadIdx.x;
    const int l  = t & 63;
    const int w  = t >> 6;
    const int lr = l & 15;
    const int lk = (l >> 4) << 3;
    const int lks = lk ^ (((l >> 1) & 3) << 3);

    const int i0 = blockIdx.y << 7;
    const int bn = blockIdx.x << 6;

    const int sr = t >> 2;
    const int sk = (((t & 3) ^ ((t >> 3) & 3)) << 3);

    const short* aS = A  + (size_t)(i0 + sr) * MM + sk;
    const short* bS = Bt + (size_t)(bn + sr) * MM + sk;

    f32x4 acc[2][4] = {};

    auto stage = [&](int sb, int k0) {
        gl2lds16(aS + k0,           &As[sb][0] + t * 8);
        gl2lds16(aS + 64 * MM + k0, &As[sb][0] + 2048 + t * 8);
        gl2lds16(bS + k0,           &Bs[sb][0] + t * 8);
    };
    stage(0, 0);

    for (int kt = 0; kt < 32; ++kt) {
        const int cur = kt & 1;
        if (kt + 1 < 32) { stage(cur ^ 1, (kt + 1) << 5); WAIT_VM3(); }
        else             { WAIT_VM0(); }
        __builtin_amdgcn_s_barrier();
        __builtin_amdgcn_sched_barrier(0);

        bf16x8 a[2], b[4];
        #pragma unroll
        for (int i = 0; i < 2; ++i)
            a[i] = *(const bf16x8*)&As[cur][(w * 32 + i * 16 + lr) * 32 + lks];
        #pragma unroll
        for (int j = 0; j < 4; ++j)
            b[j] = *(const bf16x8*)&Bs[cur][(j * 16 + lr) * 32 + lks];
        __builtin_amdgcn_s_setprio(1);
        #pragma unroll
        for (int i = 0; i < 2; ++i)
            #pragma unroll
            for (int j = 0; j < 4; ++j)
                acc[i][j] = __builtin_amdgcn_mfma_f32_16x16x32_bf16(a[i], b[j], acc[i][j], 0, 0, 0);
        __builtin_amdgcn_s_setprio(0);
        __builtin_amdgcn_s_barrier();
    }

    const int rb = (l >> 4) << 2;
    #pragma unroll
    for (int i = 0; i < 2; ++i)
        #pragma unroll
        for (int j = 0; j < 4; ++j) {
            const int n = bn + j * 16 + lr;
            #pragma unroll
            for (int r = 0; r < 4; ++r) {
                const int m = i0 + w * 32 + i * 16 + rb + r;
                C[(size_t)m * MM + n] = acc[i][j][r];
            }
        }
}

// ---------------- bilinear grid sample, 2 dword loads per sample ------------
// R13-proven best form: 4 samples/thread, row per block.
__global__ __launch_bounds__(256)
void grid_sample_k(const short* __restrict__ xh, const short* __restrict__ ofh,
                   const short* __restrict__ ofl, short* __restrict__ xnb)
{
    const int i = blockIdx.x;
    const int tid = threadIdx.x;
    const int j4 = tid << 2;

    const short* rh = ofh + (size_t)i * 2048;
    const short* rl = ofl + (size_t)i * 2048;
    s4v hx = *(const s4v*)&rh[j4];
    s4v lx = *(const s4v*)&rl[j4];
    s4v hy = *(const s4v*)&rh[1024 + j4];
    s4v ly = *(const s4v*)&rl[1024 + j4];
    s4v out;

    const float gxb = (2.0f * (float)i) / (float)NN - 1.0f;

    #pragma unroll
    for (int q = 0; q < 4; ++q) {
        const int j = j4 + q;
        float gx = gxb + b2f(hx[q]) + b2f(lx[q]);
        gx = fminf(fmaxf(gx, -1.0f), 1.0f);
        float gy = (2.0f * (float)j) / (float)MM - 1.0f + b2f(hy[q]) + b2f(ly[q]);
        gy = fminf(fmaxf(gy, -1.0f), 1.0f);

        const float ixf = (gx + 1.0f) * 511.5f;
        const float iyf = (gy + 1.0f) * 2047.5f;
        const float ix0 = floorf(ixf);
        const float iy0 = floorf(iyf);
        const float wx = ixf - ix0;
        const float wy = iyf - iy0;
        int ix0i = (int)ix0; ix0i = max(0, min(ix0i, MM - 1));
        int iy0i = (int)iy0; iy0i = max(0, min(iy0i, NN - 1));
        const int iy1i = min(iy0i + 1, NN - 1);

        const int wb = min(ix0i, MM - 2);
        const bool at_edge = ix0i > wb;

        const short* r0 = xh + (size_t)iy0i * MM + wb;
        const short* r1 = xh + (size_t)iy1i * MM + wb;
        unsigned w0, w1;
        __builtin_memcpy(&w0, r0, 4);
        __builtin_memcpy(&w1, r1, 4);

        const float v01 = b2f_hi(w0);
        const float v11 = b2f_hi(w1);
        const float v00 = at_edge ? v01 : b2f_lo(w0);
        const float v10 = at_edge ? v11 : b2f_lo(w1);

        out[q] = f2b((1.0f - wy) * ((1.0f - wx) * v00 + wx * v01)
                   + wy * ((1.0f - wx) * v10 + wx * v11));
    }
    *(s4v*)&xnb[(size_t)i * MM + j4] = out;
}

// ---------------- bf16 MFMA GEMM, BM=128 BN=128 -----------------------------
// MODE 3: banded logits -> C0 band fp32 [4096][512] with -inf mask; Bt=K
// MODE 4: fused K|V: n<1024 -> C0 = K bf16 [4096][1024]; else C1 = Vt bf16 [1024][4096]
template<int MODE>
__global__ __launch_bounds__(256, 2)
void mfma_gemm(const short* __restrict__ A, const short* __restrict__ Bt,
               void* __restrict__ C0, void* __restrict__ C1)
{
    __shared__ short As[2][128 * 32];
    __shared__ short Bs[2][128 * 32];

    const int t  = threadIdx.x;
    const int l  = t & 63;
    const int w  = t >> 6;
    const int wm = w >> 1, wn = w & 1;
    const int lr = l & 15;
    const int lk = (l >> 4) << 3;
    const int lks = lk ^ (((l >> 1) & 3) << 3);

    const int i0 = blockIdx.y << 7;
    const int bn = blockIdx.x << 7;
    const int jb = (MODE == 3) ? (i0 - 256 + bn) : bn;

    const int sr = t >> 2;
    const int sk = (((t & 3) ^ ((t >> 3) & 3)) << 3);

    const short* aS = A + (size_t)(i0 + sr) * MM + sk;
    int br0 = jb + sr, br1 = jb + sr + 64;
    if (MODE == 3) {
        br0 = min(max(br0, 0), NN - 1);
        br1 = min(max(br1, 0), NN - 1);
    }
    const short* bS0 = Bt + (size_t)br0 * MM + sk;
    const short* bS1 = Bt + (size_t)br1 * MM + sk;

    f32x4 acc[4][4] = {};

    auto stage = [&](int sb, int k0) {
        gl2lds16(aS + k0,           &As[sb][0] + t * 8);
        gl2lds16(aS + 64 * MM + k0, &As[sb][0] + 2048 + t * 8);
        gl2lds16(bS0 + k0,          &Bs[sb][0] + t * 8);
        gl2lds16(bS1 + k0,          &Bs[sb][0] + 2048 + t * 8);
    };
    stage(0, 0);

    for (int kt = 0; kt < 32; ++kt) {
        const int cur = kt & 1;
        if (kt + 1 < 32) { stage(cur ^ 1, (kt + 1) << 5); WAIT_VM4(); }
        else             { WAIT_VM0(); }
        __builtin_amdgcn_s_barrier();
        __builtin_amdgcn_sched_barrier(0);

        bf16x8 a[4], b[4];
        #pragma unroll
        for (int i = 0; i < 4; ++i)
            a[i] = *(const bf16x8*)&As[cur][(wm * 64 + i * 16 + lr) * 32 + lks];
        #pragma unroll
        for (int j = 0; j < 4; ++j)
            b[j] = *(const bf16x8*)&Bs[cur][(wn * 64 + j * 16 + lr) * 32 + lks];
        __builtin_amdgcn_s_setprio(1);
        #pragma unroll
        for (int i = 0; i < 4; ++i)
            #pragma unroll
            for (int j = 0; j < 4; ++j)
                acc[i][j] = __builtin_amdgcn_mfma_f32_16x16x32_bf16(a[i], b[j], acc[i][j], 0, 0, 0);
        __builtin_amdgcn_s_setprio(0);
        __builtin_amdgcn_s_barrier();
    }

    const int rb = (l >> 4) << 2;
    #pragma unroll
    for (int i = 0; i < 4; ++i) {
        #pragma unroll
        for (int j = 0; j < 4; ++j) {
            const int nl = wn * 64 + j * 16 + lr;
            if (MODE == 4 && bn + nl >= 1024) {
                const int m0 = i0 + wm * 64 + i * 16 + rb;
                s4v o;
                #pragma unroll
                for (int r = 0; r < 4; ++r) o[r] = f2b(acc[i][j][r]);
                *(s4v*)&((short*)C1)[(size_t)(bn + nl - 1024) * NN + m0] = o;
            } else {
                #pragma unroll
                for (int r = 0; r < 4; ++r) {
                    const int m = i0 + wm * 64 + i * 16 + rb + r;
                    const float v = acc[i][j][r];
                    if (MODE == 4) {
                        ((short*)C0)[(size_t)m * MM + bn + nl] = f2b(v);
                    } else if (MODE == 3) {
                        const int jj = jb + nl;
                        const int ci = jj - m + 255;
                        if (ci >= 0 && ci <= 510)
                            ((float*)C0)[(size_t)m * BANDP + ci] =
                                (jj >= 0 && jj < NN) ? 0.06f * v : -INFINITY;
                    }
                }
            }
        }
    }
}

// ---------------- softmax over band; scatter att values + bandT -------------
__global__ __launch_bounds__(256)
void band_softmax(const float* __restrict__ band, float* __restrict__ att,
                  short* __restrict__ bandT)
{
    const int i = blockIdx.x;
    const int tid = threadIdx.x;
    const float* brow = band + (size_t)i * BANDP;

    float v0 = brow[tid];
    float v1 = (tid < 255) ? brow[tid + 256] : -INFINITY;

    float m = fmaxf(v0, v1);
    #pragma unroll
    for (int o = 32; o >= 1; o >>= 1) m = fmaxf(m, __shfl_xor(m, o));
    __shared__ float redm[4], reds[4];
    const int wv = tid >> 6, ln = tid & 63;
    if (ln == 0) redm[wv] = m;
    __syncthreads();
    m = fmaxf(fmaxf(redm[0], redm[1]), fmaxf(redm[2], redm[3]));

    float p0 = expf(v0 - m);
    float p1 = (tid < 255) ? expf(v1 - m) : 0.f;
    float s = p0 + p1;
    #pragma unroll
    for (int o = 32; o >= 1; o >>= 1) s += __shfl_xor(s, o);
    if (ln == 0) reds[wv] = s;
    __syncthreads();
    s = reds[0] + reds[1] + reds[2] + reds[3];
    const float rinv = 1.0f / s;
    p0 *= rinv; p1 *= rinv;

    float* arow = att + (size_t)i * NN;
    int j = i + tid - 255;
    if (j >= 0 && j < NN) {
        arow[j] = p0;
        bandT[(size_t)j * 768 + (i - (j & ~7) + 384)] = f2b(p0);
    }
    j = i + tid + 1;
    if (tid < 255 && j >= 0 && j < NN) {
        arow[j] = p1;
        bandT[(size_t)j * 768 + (i - (j & ~7) + 384)] = f2b(p1);
    }
}

// ---------------- y1 = att^T @ V via MFMA, direct-global operands -----------
__global__ __launch_bounds__(256, 2)
void attT_v_mfma(const short* __restrict__ bandT, const short* __restrict__ Vt,
                 short* __restrict__ y1b)
{
    const int t = threadIdx.x, l = t & 63, w = t >> 6;
    const int wm = w >> 1, wn = w & 1;
    const int lr = l & 15, lk = (l >> 4) << 3;
    const int r0 = blockIdx.y << 7;
    const int n0 = blockIdx.x << 6;

    f32x4 acc[4][2] = {};
    for (int ks = 0; ks < 20; ++ks) {
        const int j0 = r0 - 256 + (ks << 5);
        if (j0 < 0 || j0 >= NN) continue;
        bf16x8 b[2];
        #pragma unroll
        for (int j = 0; j < 2; ++j)
            b[j] = *(const bf16x8*)&Vt[(size_t)(n0 + wn * 32 + j * 16 + lr) * NN + j0 + lk];
        #pragma unroll
        for (int i = 0; i < 4; ++i) {
            const int r = r0 + wm * 64 + i * 16 + lr;
            const int cc = j0 + lk - (r & ~7) + 384;
            bf16x8 a = *(const bf16x8*)&bandT[(size_t)r * 768 + cc];
            #pragma unroll
            for (int j = 0; j < 2; ++j)
                acc[i][j] = __builtin_amdgcn_mfma_f32_16x16x32_bf16(a, b[j], acc[i][j], 0, 0, 0);
        }
    }
    const int rb = (l >> 4) << 2;
    #pragma unroll
    for (int i = 0; i < 4; ++i)
        #pragma unroll
        for (int j = 0; j < 2; ++j)
            #pragma unroll
            for (int r = 0; r < 4; ++r)
                y1b[(size_t)(r0 + wm * 64 + i * 16 + rb + r) * MM + n0 + wn * 32 + j * 16 + lr]
                    = f2b(acc[i][j][r]);
}

extern "C" void kernel_launch(void* const* d_in, const int* in_sizes, int n_in,
                              void* d_out, int out_size, void* d_ws, size_t ws_size,
                              hipStream_t stream)
{
    const float* x    = (const float*)d_in[0];
    const float* Wq   = (const float*)d_in[1];
    const float* Wk   = (const float*)d_in[2];
    const float* Wv   = (const float*)d_in[3];
    const float* Wofx = (const float*)d_in[4];
    const float* bofx = (const float*)d_in[5];
    const float* Wofy = (const float*)d_in[6];
    const float* bofy = (const float*)d_in[7];
    const float* Wout = (const float*)d_in[8];

    float* y_out   = (float*)d_out;
    float* att_out = (float*)d_out + (size_t)NN * MM;

    char* wsb = (char*)d_ws;
    const size_t MB = 1024 * 1024;
    // Layout identical to R13 (liveness-verified, peak 64 MB at ofxy-GEMM):
    short* xh      = (short*)(wsb + 0);         // 8 MB
    short* Qh      = (short*)(wsb + 8 * MB);    // 8 MB
    short* Ql      = (short*)(wsb + 16 * MB);   // 8 MB
    short* WofxyTh = (short*)(wsb + 24 * MB);   // 4 MB (2 planes)
    short* WofxyTl = (short*)(wsb + 28 * MB);   // 4 MB
    short* xl      = (short*)(wsb + 32 * MB);   // 8 MB (dead after Q-GEMM)
    short* WqTh    = (short*)(wsb + 40 * MB);   // 2 MB
    short* WqTl    = (short*)(wsb + 42 * MB);   // 2 MB
    short* ofxyh   = (short*)(wsb + 32 * MB);   // 16 MB (over xl/WqT dead)
    short* ofxyl   = (short*)(wsb + 48 * MB);   // 16 MB
    short* xnb     = (short*)(wsb + 16 * MB);   // 8 MB (over Ql dead)
    short* WkvT    = (short*)(wsb + 24 * MB);   // 4 MB (over WofxyT dead)
    short* WoutT   = (short*)(wsb + 28 * MB);   // 2 MB
    short* Kb      = (short*)(wsb + 32 * MB);   // 8 MB (over ofxyh dead)
    short* Vtb     = (short*)(wsb + 40 * MB);   // 8 MB
    float* band    = (float*)(wsb + 48 * MB);   // 8 MB (over ofxyl dead)
    short* bandT   = (short*)(wsb + 56 * MB);   // 6 MB
    short* y1b     = (short*)(wsb + 16 * MB);   // 8 MB (over xnb dead)

    const dim3 blk(256);
    const dim3 tblk(32, 8);

    // ---- fused prep: split x + trsplit Wq/Wofx/Wofy ----
    prep_k<<<dim3(32, 32, 7), tblk, 0, stream>>>(
        x, Wq, Wofx, Wofy, xh, xl, WqTh, WqTl, WofxyTh, WofxyTl);

    // ---- sensitive path via split-bf16 MFMA ----
    gemm_split64<<<dim3(16, 32), blk, 0, stream>>>(
        xh, xl, WqTh, WqTl, Qh, Ql, 1024);
    gemm_split<true><<<dim3(16, 32), blk, 0, stream>>>(
        Qh, Ql, WofxyTh, WofxyTl, bofx, bofy, ofxyh, ofxyl, 2048);

    // gather from bf16 x (xh), 2 dword loads per sample (R13-proven form)
    grid_sample_k<<<dim3(NN), blk, 0, stream>>>(xh, ofxyh, ofxyl, xnb);

    // ---- bf16 path ----
    transpose3_k<<<dim3(32, 32, 3), tblk, 0, stream>>>(Wk, Wv, Wout, WkvT, WoutT);

    // K | Vt fused
    mfma_gemm<4><<<dim3(16, 32), blk, 0, stream>>>(xnb, WkvT, Kb, Vtb);
    // banded logits
    mfma_gemm<3><<<dim3(5, 32), blk, 0, stream>>>(Qh, Kb, band, nullptr);
    // zero att region (64 MB) + bandT, then scatter-only softmax
    hipMemsetAsync(att_out, 0, (size_t)NN * NN * sizeof(float), stream);
    hipMemsetAsync(bandT, 0, (size_t)NN * 768 * sizeof(short), stream);
    band_softmax<<<dim3(NN), blk, 0, stream>>>(band, att_out, bandT);
    // y1 = att^T @ V
    attT_v_mfma<<<dim3(16, 32), blk, 0, stream>>>(bandT, Vtb, y1b);
    // y = y1 @ Wout
    gemm64_f32out<<<dim3(16, 32), blk, 0, stream>>>(y1b, WoutT, y_out);
}